// Round 3
// baseline (265.095 us; speedup 1.0000x reference)
//
#include <hip/hip_runtime.h>

#define NN 50000
#define NE 800000
#define DD 128

// NOTE (harness contract): integer inputs are delivered as int32 regardless of
// the reference's int64 — edge_index is `const int*` with 2*NE elements.
// Round-2 core dump was caused by casting it to long long (2x OOB reads).

// ---------------- zero the degree array (ws is poisoned 0xAA every call) ----
__global__ __launch_bounds__(256) void k_zero(int* __restrict__ deg) {
  int i = blockIdx.x * 256 + threadIdx.x;
  if (i < NN) deg[i] = 0;
}

// ---------------- h = x @ W.T  (fp32 vector GEMM, W transposed in LDS) ------
// block = 512 threads, 64 rows/block (64KB LDS -> 2 blocks/CU -> 16 waves/CU).
// Thread t: cg=t&31 -> 4 consecutive cols, rg=t>>5 -> 4 rows.
__global__ __launch_bounds__(512) void k_gemm(const float* __restrict__ x,
                                              const float* __restrict__ W,
                                              float* __restrict__ h) {
  __shared__ float Wt[DD * DD];  // Wt[k*128 + j] = W[j*128 + k]
  const int t = threadIdx.x;
  {
    // thread t loads quarter-row j=t>>2, k-quarter=(t&3)*32.
    const int j = t >> 2;
    const int kb = (t & 3) * 32;
    const float4* wrow = (const float4*)(W + j * DD + kb);
#pragma unroll
    for (int i = 0; i < 8; ++i) {
      float4 v = wrow[i];
      int k = kb + i * 4;
      Wt[(k + 0) * DD + j] = v.x;
      Wt[(k + 1) * DD + j] = v.y;
      Wt[(k + 2) * DD + j] = v.z;
      Wt[(k + 3) * DD + j] = v.w;
    }
  }
  __syncthreads();

  const int cg = t & 31;
  const int rg = t >> 5;  // 0..15
  const int c0 = cg * 4;
  const int rbase = blockIdx.x * 64 + rg * 4;

  float acc[4][4];
#pragma unroll
  for (int a = 0; a < 4; ++a)
#pragma unroll
    for (int c = 0; c < 4; ++c) acc[a][c] = 0.f;

  const float* xp[4];
#pragma unroll
  for (int rr = 0; rr < 4; ++rr) {
    int r = rbase + rr;
    if (r > NN - 1) r = NN - 1;  // clamp loads; stores guarded below
    xp[rr] = x + (size_t)r * DD;
  }

  for (int k = 0; k < DD; k += 4) {
    float4 xv[4];
#pragma unroll
    for (int rr = 0; rr < 4; ++rr) xv[rr] = *(const float4*)(xp[rr] + k);
#pragma unroll
    for (int kk = 0; kk < 4; ++kk) {
      float4 w = *(const float4*)(&Wt[(k + kk) * DD + c0]);
#pragma unroll
      for (int rr = 0; rr < 4; ++rr) {
        float a = (&xv[rr].x)[kk];
        acc[rr][0] += a * w.x;
        acc[rr][1] += a * w.y;
        acc[rr][2] += a * w.z;
        acc[rr][3] += a * w.w;
      }
    }
  }
#pragma unroll
  for (int rr = 0; rr < 4; ++rr) {
    int r = rbase + rr;
    if (r < NN) {
      *(float4*)(h + (size_t)r * DD + c0) =
          make_float4(acc[rr][0], acc[rr][1], acc[rr][2], acc[rr][3]);
    }
  }
}

// ---------------- histogram of dst --------------------------------------------
__global__ __launch_bounds__(256) void k_hist(const int* __restrict__ ei,
                                              int* __restrict__ deg) {
  int e = blockIdx.x * 256 + threadIdx.x;  // grid sized exactly NE/256
  int d = ei[NE + e];
  atomicAdd(&deg[d], 1);
}

// ---------------- 2-level exclusive scan over deg -----------------------------
__global__ __launch_bounds__(256) void k_scan1(const int* __restrict__ deg,
                                               int* __restrict__ tmp,
                                               int* __restrict__ bsum) {
  __shared__ int s[256];
  int t = threadIdx.x;
  int i = blockIdx.x * 256 + t;
  int v = (i < NN) ? deg[i] : 0;
  s[t] = v;
  __syncthreads();
  for (int off = 1; off < 256; off <<= 1) {
    int u = (t >= off) ? s[t - off] : 0;
    __syncthreads();
    s[t] += u;
    __syncthreads();
  }
  if (i < NN) tmp[i] = s[t];                       // block-local inclusive
  if (t == 255) bsum[blockIdx.x] = s[255];         // block total
}

__global__ __launch_bounds__(256) void k_scan2(int* __restrict__ bsum) {
  __shared__ int s[256];
  int t = threadIdx.x;
  int v = (t < 196) ? bsum[t] : 0;  // 196 = ceil(NN/256)
  s[t] = v;
  __syncthreads();
  for (int off = 1; off < 256; off <<= 1) {
    int u = (t >= off) ? s[t - off] : 0;
    __syncthreads();
    s[t] += u;
    __syncthreads();
  }
  if (t < 196) bsum[t] = s[t] - v;  // exclusive block offsets
}

__global__ __launch_bounds__(256) void k_scan3(const int* __restrict__ tmp,
                                               const int* __restrict__ bsum,
                                               const int* __restrict__ deg,
                                               int* __restrict__ row_start,
                                               int* __restrict__ cursor) {
  int i = blockIdx.x * 256 + threadIdx.x;
  if (i < NN) {
    int incl = tmp[i] + bsum[i >> 8];
    row_start[i + 1] = incl;            // row_start[i+1] = inclusive prefix
    cursor[i] = incl - deg[i];          // = row_start[i]
    if (i == 0) row_start[0] = 0;
  }
}

// ---------------- scatter edges into CSR buckets ------------------------------
__global__ __launch_bounds__(256) void k_scatter(const int* __restrict__ ei,
                                                 int* __restrict__ cursor,
                                                 int* __restrict__ csr) {
  int e = blockIdx.x * 256 + threadIdx.x;
  int s = ei[e];
  int d = ei[NE + e];
  int p = atomicAdd(&cursor[d], 1);
  csr[p] = s;
}

// ---------------- per-node gather-reduce (no fp32 atomics) --------------------
// One wave per node; lane owns 2 dims (float2, 512B/row coalesced).
// Inner loop unrolled x4 (4 independent row-loads in flight per lane).
__global__ __launch_bounds__(256) void k_gather(const float* __restrict__ h,
                                                const int* __restrict__ csr,
                                                const int* __restrict__ row_start,
                                                const float* __restrict__ bias,
                                                float* __restrict__ out) {
  int node = blockIdx.x * 4 + (threadIdx.x >> 6);
  int lane = threadIdx.x & 63;
  int beg = row_start[node];
  int end = row_start[node + 1];
  float2 acc = make_float2(0.f, 0.f);
  for (int j0 = beg; j0 < end; j0 += 64) {
    int sv = 0;
    if (j0 + lane < end) sv = csr[j0 + lane];  // batch 64 src ids into regs
    int cnt = end - j0;
    if (cnt > 64) cnt = 64;
    int i = 0;
    for (; i + 4 <= cnt; i += 4) {
      int s0 = __shfl(sv, i + 0, 64);
      int s1 = __shfl(sv, i + 1, 64);
      int s2 = __shfl(sv, i + 2, 64);
      int s3 = __shfl(sv, i + 3, 64);
      float2 v0 = *(const float2*)(h + (size_t)s0 * DD + lane * 2);
      float2 v1 = *(const float2*)(h + (size_t)s1 * DD + lane * 2);
      float2 v2 = *(const float2*)(h + (size_t)s2 * DD + lane * 2);
      float2 v3 = *(const float2*)(h + (size_t)s3 * DD + lane * 2);
      acc.x += v0.x; acc.y += v0.y;
      acc.x += v1.x; acc.y += v1.y;
      acc.x += v2.x; acc.y += v2.y;
      acc.x += v3.x; acc.y += v3.y;
    }
    for (; i < cnt; ++i) {
      int s = __shfl(sv, i, 64);
      const float2 v = *(const float2*)(h + (size_t)s * DD + lane * 2);
      acc.x += v.x;
      acc.y += v.y;
    }
  }
  float2 bb = *(const float2*)(bias + lane * 2);
  acc.x += bb.x;
  acc.y += bb.y;
  *(float2*)(out + (size_t)node * DD + lane * 2) = acc;
}

// ---------------- launch ------------------------------------------------------
extern "C" void kernel_launch(void* const* d_in, const int* in_sizes, int n_in,
                              void* d_out, int out_size, void* d_ws, size_t ws_size,
                              hipStream_t stream) {
  const float* x = (const float*)d_in[0];
  const int* ei = (const int*)d_in[1];  // [2, NE], harness delivers int32
  const float* W = (const float*)d_in[2];
  const float* b = (const float*)d_in[3];
  float* out = (float*)d_out;

  // workspace carve-up (~29.6 MB)
  float* h = (float*)d_ws;                    // NN*DD floats
  int* deg = (int*)(h + (size_t)NN * DD);     // NN
  int* row_start = deg + NN;                  // NN+1
  int* cursor = row_start + (NN + 1);         // NN
  int* tmp = cursor + NN;                     // NN
  int* bsum = tmp + NN;                       // 256
  int* csr = bsum + 256;                      // NE

  k_zero<<<(NN + 255) / 256, 256, 0, stream>>>(deg);
  k_gemm<<<(NN + 63) / 64, 512, 0, stream>>>(x, W, h);
  k_hist<<<NE / 256, 256, 0, stream>>>(ei, deg);
  k_scan1<<<(NN + 255) / 256, 256, 0, stream>>>(deg, tmp, bsum);
  k_scan2<<<1, 256, 0, stream>>>(bsum);
  k_scan3<<<(NN + 255) / 256, 256, 0, stream>>>(tmp, bsum, deg, row_start, cursor);
  k_scatter<<<NE / 256, 256, 0, stream>>>(ei, cursor, csr);
  k_gather<<<NN / 4, 256, 0, stream>>>(h, csr, row_start, b, out);
}